// Round 1
// baseline (399.762 us; speedup 1.0000x reference)
//
#include <hip/hip_runtime.h>
#include <cstdint>
#include <cstddef>

#define TT   512   // sequence length
#define MT   16    // batch per block (one MFMA N-tile)
#define OUTN 30    // output features

typedef __attribute__((ext_vector_type(8))) short short8;
typedef __attribute__((ext_vector_type(4))) float floatx4;

static __device__ __forceinline__ float fast_sigmoid(float x) {
    float e = __builtin_amdgcn_exp2f(-1.4426950408889634f * x);
    return __builtin_amdgcn_rcpf(1.0f + e);
}
static __device__ __forceinline__ float fast_tanh(float x) {
    float e = __builtin_amdgcn_exp2f(-2.8853900817779268f * x);
    return 2.0f * __builtin_amdgcn_rcpf(1.0f + e) - 1.0f;
}
static __device__ __forceinline__ unsigned short to_bf16(float f) {
    union { float f; unsigned int u; } v; v.f = f;
    return (unsigned short)((v.u + 0x7FFFu + ((v.u >> 16) & 1u)) >> 16);
}

// Load 8 consecutive bf16-converted weights from row-major [128][32].
// arow is the PERMUTED row index: perm row R holds original row (R&3)*32 + (R>>2)
// i.e. rows ordered [i0,f0,g0,o0, i1,f1,g1,o1, ...].
static __device__ __forceinline__ short8 load_frag_perm(const float* __restrict__ W, int arow, int k0) {
    int orig = (arow & 3) * 32 + (arow >> 2);
    const float* p = W + orig * 32 + k0;
    short8 s;
#pragma unroll
    for (int e = 0; e < 8; ++e) s[e] = (short)to_bf16(p[e]);
    return s;
}
static __device__ __forceinline__ short8 load_frag_plain(const float* __restrict__ W, int row, int k0) {
    const float* p = W + row * 32 + k0;
    short8 s;
#pragma unroll
    for (int e = 0; e < 8; ++e) s[e] = (short)to_bf16(p[e]);
    return s;
}

// Grid: 256 blocks (one per 16-batch tile). Block: 512 threads = 8 waves.
// Wave w owns permuted gate-rows [16w, 16w+16) = hidden units 4w..4w+3 (all layers).
// Lane l: batch b = l&15, q = l>>4, owned unit u = 4w+q.
// Zt = Wperm @ H^T per layer via mfma_f32_16x16x32_bf16:
//   A-frag: row = l&15 (within tile), k = q*8+e  (weights, VGPR-resident)
//   B-frag: col = l&15 = batch,      k = q*8+e  -> one ds_read_b128 from h LDS buf
//   D:      col = l&15 = batch, row-in-tile = q*4+r  ->  gate r of unit u : lane-local!
__global__ __launch_bounds__(512, 2) void lstm_fused(
    const float* __restrict__ x,
    const float* __restrict__ Wih0, const float* __restrict__ Whh0,
    const float* __restrict__ bih0, const float* __restrict__ bhh0,
    const float* __restrict__ Wih1, const float* __restrict__ Whh1,
    const float* __restrict__ bih1, const float* __restrict__ bhh1,
    const float* __restrict__ Wih2, const float* __restrict__ Whh2,
    const float* __restrict__ bih2, const float* __restrict__ bhh2,
    const float* __restrict__ W2,   const float* __restrict__ b2,
    float* __restrict__ out)
{
    __shared__ float xs[MT][TT + 4];            // 33 KB, +4 pad kills bank conflicts
    __shared__ unsigned short h0s[MT][40];      // bf16 h, 80B rows: b128-aligned, ~2-way banks
    __shared__ unsigned short h1s[MT][40];
    __shared__ unsigned short h2s[2][MT][40];   // double-buffered (read t&1, write (t+1)&1)

    const int tid  = (int)threadIdx.x;
    const int w    = tid >> 6;
    const int l    = tid & 63;
    const int b    = l & 15;
    const int q    = l >> 4;
    const int u    = 4 * w + q;
    const int bt   = (int)blockIdx.x;
    const int arow = 16 * w + b;     // A-frag row (lane&15 mapping)
    const int k0   = q * 8;          // shared k-map for A and B fragments

    // ---- stage x tile [16][512] (contiguous 32KB) ----
    {
        const floatx4* xg = (const floatx4*)(x + (size_t)bt * MT * TT);
#pragma unroll
        for (int j = 0; j < 4; ++j) {
            int idx = tid + j * 512;       // float4 index, 2048 total
            int row = idx >> 7;            // /128 float4 per row
            int c4  = idx & 127;
            floatx4 v = xg[idx];
            *(floatx4*)&xs[row][c4 * 4] = v;
        }
    }
    // zero h state buffers
    for (int i = tid; i < MT * 40; i += 512) {
        ((unsigned short*)h0s)[i] = 0;
        ((unsigned short*)h1s)[i] = 0;
        ((unsigned short*)h2s)[i] = 0;
        ((unsigned short*)h2s)[MT * 40 + i] = 0;
    }

    // ---- weight fragments, VGPR-resident for the whole kernel ----
    short8 whh0f = load_frag_perm(Whh0, arow, k0);
    short8 wih1f = load_frag_perm(Wih1, arow, k0);
    short8 whh1f = load_frag_perm(Whh1, arow, k0);
    short8 wih2f = load_frag_perm(Wih2, arow, k0);
    short8 whh2f = load_frag_perm(Whh2, arow, k0);

    // layer-0 input weights (IN=1 -> rank-1, folded into epilogue) + fused biases
    float wx0[4], bz0[4], bz1[4], bz2[4];
#pragma unroll
    for (int r = 0; r < 4; ++r) {
        int idx = r * 32 + u;            // gate r, unit u -> original row
        wx0[r] = Wih0[idx];
        bz0[r] = bih0[idx] + bhh0[idx];
        bz1[r] = bih1[idx] + bhh1[idx];
        bz2[r] = bih2[idx] + bhh2[idx];
    }

    // final projection fragments (waves 0,1 cover rows 0..31, mask >=30)
    short8 w2f = {};
    float b2v[4] = {0.f, 0.f, 0.f, 0.f};
    if (w < 2) {
        int r2 = 16 * w + b;
        int rc = r2 < OUTN ? r2 : OUTN - 1;   // clamp: avoid OOB read, masked at store
        w2f = load_frag_plain(W2, rc, k0);
#pragma unroll
        for (int r = 0; r < 4; ++r) {
            int rr = 16 * w + 4 * q + r;
            b2v[r] = (rr < OUTN) ? b2[rr] : 0.0f;
        }
    }

    float c0 = 0.f, c1 = 0.f, c2 = 0.f;
    const floatx4 zero4 = {0.f, 0.f, 0.f, 0.f};

    __syncthreads();   // x staged, h zeroed, weights ready

    for (int t = 0; t < TT; ++t) {
        // --- top: read all previous-step h (old values) and start Whh matmuls ---
        short8 bf0 = *(const short8*)&h0s[b][k0];
        short8 bf1 = *(const short8*)&h1s[b][k0];
        short8 bf2 = *(const short8*)&h2s[t & 1][b][k0];
        floatx4 z0 = __builtin_amdgcn_mfma_f32_16x16x32_bf16(whh0f, bf0, zero4, 0, 0, 0);
        floatx4 z1 = __builtin_amdgcn_mfma_f32_16x16x32_bf16(whh1f, bf1, zero4, 0, 0, 0);
        floatx4 z2 = __builtin_amdgcn_mfma_f32_16x16x32_bf16(whh2f, bf2, zero4, 0, 0, 0);

        // --- layer 0 (input term is rank-1: x[b][t] * wih0) ---
        float xv = xs[b][t];
        float i0 = fast_sigmoid(z0[0] + xv * wx0[0] + bz0[0]);
        float f0 = fast_sigmoid(z0[1] + xv * wx0[1] + bz0[1]);
        float g0 = fast_tanh   (z0[2] + xv * wx0[2] + bz0[2]);
        float o0 = fast_sigmoid(z0[3] + xv * wx0[3] + bz0[3]);
        c0 = f0 * c0 + i0 * g0;
        float h0 = o0 * fast_tanh(c0);

        __syncthreads();                    // B1: all reads of h*(t-1) complete
        h0s[b][u] = to_bf16(h0);
        __syncthreads();                    // B2: h0(t) visible

        // --- layer 1: z1 += Wih1 @ h0(t)^T ---
        short8 bh0 = *(const short8*)&h0s[b][k0];
        z1 = __builtin_amdgcn_mfma_f32_16x16x32_bf16(wih1f, bh0, z1, 0, 0, 0);
        float i1 = fast_sigmoid(z1[0] + bz1[0]);
        float f1 = fast_sigmoid(z1[1] + bz1[1]);
        float g1 = fast_tanh   (z1[2] + bz1[2]);
        float o1 = fast_sigmoid(z1[3] + bz1[3]);
        c1 = f1 * c1 + i1 * g1;
        float h1 = o1 * fast_tanh(c1);
        h1s[b][u] = to_bf16(h1);            // safe: readers of h1(t-1) done at B1
        __syncthreads();                    // B3: h1(t) visible

        // --- layer 2: z2 += Wih2 @ h1(t)^T ---
        short8 bh1 = *(const short8*)&h1s[b][k0];
        z2 = __builtin_amdgcn_mfma_f32_16x16x32_bf16(wih2f, bh1, z2, 0, 0, 0);
        float i2 = fast_sigmoid(z2[0] + bz2[0]);
        float f2 = fast_sigmoid(z2[1] + bz2[1]);
        float g2 = fast_tanh   (z2[2] + bz2[2]);
        float o2 = fast_sigmoid(z2[3] + bz2[3]);
        c2 = f2 * c2 + i2 * g2;
        float h2 = o2 * fast_tanh(c2);
        h2s[(t + 1) & 1][b][u] = to_bf16(h2);   // safe: prior readers of this buf done at B1(t)
    }
    __syncthreads();   // h2(T-1) in h2s[0] visible

    // ---- out = h2_last @ W2^T + b2, as out^T = W2 @ h2^T (waves 0,1) ----
    if (w < 2) {
        short8 bh2 = *(const short8*)&h2s[0][b][k0];
        floatx4 zo = __builtin_amdgcn_mfma_f32_16x16x32_bf16(w2f, bh2, zero4, 0, 0, 0);
#pragma unroll
        for (int r = 0; r < 4; ++r) {
            int rr = 16 * w + 4 * q + r;
            if (rr < OUTN)
                out[(size_t)(bt * MT + b) * OUTN + rr] = zo[r] + b2v[r];
        }
    }
}

extern "C" void kernel_launch(void* const* d_in, const int* in_sizes, int n_in,
                              void* d_out, int out_size, void* d_ws, size_t ws_size,
                              hipStream_t stream) {
    const float* x    = (const float*)d_in[0];
    const float* Wih0 = (const float*)d_in[1];
    const float* Whh0 = (const float*)d_in[2];
    const float* bih0 = (const float*)d_in[3];
    const float* bhh0 = (const float*)d_in[4];
    const float* Wih1 = (const float*)d_in[5];
    const float* Whh1 = (const float*)d_in[6];
    const float* bih1 = (const float*)d_in[7];
    const float* bhh1 = (const float*)d_in[8];
    const float* Wih2 = (const float*)d_in[9];
    const float* Whh2 = (const float*)d_in[10];
    const float* bih2 = (const float*)d_in[11];
    const float* bhh2 = (const float*)d_in[12];
    const float* W2   = (const float*)d_in[13];
    const float* b2   = (const float*)d_in[14];
    float* out = (float*)d_out;

    dim3 grid(4096 / MT);   // 256 blocks
    dim3 block(512);        // 8 waves
    hipLaunchKernelGGL(lstm_fused, grid, block, 0, stream,
                       x, Wih0, Whh0, bih0, bhh0,
                       Wih1, Whh1, bih1, bhh1,
                       Wih2, Whh2, bih2, bhh2, W2, b2, out);
}

// Round 2
// 283.888 us; speedup vs baseline: 1.4082x; 1.4082x over previous
//
#include <hip/hip_runtime.h>
#include <cstdint>
#include <cstddef>

#define TT   512   // sequence length
#define MT   16    // batch per block (one MFMA N-tile)
#define OUTN 30    // output features

typedef __attribute__((ext_vector_type(8))) short short8;
typedef __attribute__((ext_vector_type(4))) float floatx4;

static __device__ __forceinline__ float fast_sigmoid(float x) {
    float e = __builtin_amdgcn_exp2f(-1.4426950408889634f * x);
    return __builtin_amdgcn_rcpf(1.0f + e);
}
static __device__ __forceinline__ float fast_tanh(float x) {
    float e = __builtin_amdgcn_exp2f(-2.8853900817779268f * x);
    return 2.0f * __builtin_amdgcn_rcpf(1.0f + e) - 1.0f;
}
static __device__ __forceinline__ unsigned short to_bf16(float f) {
    union { float f; unsigned int u; } v; v.f = f;
    return (unsigned short)((v.u + 0x7FFFu + ((v.u >> 16) & 1u)) >> 16);
}

// Load 8 consecutive bf16-converted weights from row-major [128][32].
// perm row R holds original row (R&3)*32 + (R>>2): order [i0,f0,g0,o0, i1,...]
static __device__ __forceinline__ short8 load_frag_perm(const float* __restrict__ W, int arow, int k0) {
    int orig = (arow & 3) * 32 + (arow >> 2);
    const float* p = W + orig * 32 + k0;
    short8 s;
#pragma unroll
    for (int e = 0; e < 8; ++e) s[e] = (short)to_bf16(p[e]);
    return s;
}
static __device__ __forceinline__ short8 load_frag_plain(const float* __restrict__ W, int row, int k0) {
    const float* p = W + row * 32 + k0;
    short8 s;
#pragma unroll
    for (int e = 0; e < 8; ++e) s[e] = (short)to_bf16(p[e]);
    return s;
}

// Grid: 256 blocks (16-batch tiles). Block: 512 threads = 8 waves.
// Wave wv owns permuted gate-rows [16wv,16wv+16) = units 4wv..4wv+3.
// Lane l: b=l&15 (batch/MFMA col), q=l>>4, unit u=4wv+q, k-chunk k0=8q.
// Software pipeline: iter k computes layer0@t=k, layer1@t=k-1, layer2@t=k-2.
// All 5 MFMAs read only last-iteration h -> ONE barrier per iteration.
// h layout [buf][q-chunk][b][8 u16]: ds_read_b128 addr16 == laneid (conflict-free).
__global__ __launch_bounds__(512, 2) void lstm_fused(
    const float* __restrict__ x,
    const float* __restrict__ Wih0, const float* __restrict__ Whh0,
    const float* __restrict__ bih0, const float* __restrict__ bhh0,
    const float* __restrict__ Wih1, const float* __restrict__ Whh1,
    const float* __restrict__ bih1, const float* __restrict__ bhh1,
    const float* __restrict__ Wih2, const float* __restrict__ Whh2,
    const float* __restrict__ bih2, const float* __restrict__ bhh2,
    const float* __restrict__ W2,   const float* __restrict__ b2,
    float* __restrict__ out)
{
    __shared__ float xs[MT][TT + 4];                // stride 516: 2-way banks max
    __shared__ unsigned short h0s[2][4][MT][8];     // 1KB x2, linear-in-lane reads
    __shared__ unsigned short h1s[2][4][MT][8];
    __shared__ unsigned short h2s[2][4][MT][8];

    const int tid  = (int)threadIdx.x;
    const int wv   = tid >> 6;
    const int l    = tid & 63;
    const int b    = l & 15;
    const int q    = l >> 4;
    const int u    = 4 * wv + q;
    const int uc   = u >> 3, ue = u & 7;
    const int bt   = (int)blockIdx.x;
    const int arow = 16 * wv + b;
    const int k0   = q * 8;

    // ---- stage x tile [16][512] ----
    {
        const floatx4* xg = (const floatx4*)(x + (size_t)bt * MT * TT);
#pragma unroll
        for (int j = 0; j < 4; ++j) {
            int idx = tid + j * 512;
            int row = idx >> 7;
            int c4  = idx & 127;
            *(floatx4*)&xs[row][c4 * 4] = xg[idx];
        }
    }
    // zero h buffers (h(t<0) = 0; inactive pipeline stages never write)
    {
        unsigned short* p0 = (unsigned short*)h0s;
        unsigned short* p1 = (unsigned short*)h1s;
        unsigned short* p2 = (unsigned short*)h2s;
        for (int i = tid; i < 2 * 4 * MT * 8; i += 512) { p0[i] = 0; p1[i] = 0; p2[i] = 0; }
    }

    // ---- VGPR-resident weight fragments ----
    short8 whh0f = load_frag_perm(Whh0, arow, k0);
    short8 wih1f = load_frag_perm(Wih1, arow, k0);
    short8 whh1f = load_frag_perm(Whh1, arow, k0);
    short8 wih2f = load_frag_perm(Wih2, arow, k0);
    short8 whh2f = load_frag_perm(Whh2, arow, k0);

    float wx0[4], bz0[4], bz1[4], bz2[4];
#pragma unroll
    for (int r = 0; r < 4; ++r) {
        int idx = r * 32 + u;
        wx0[r] = Wih0[idx];
        bz0[r] = bih0[idx] + bhh0[idx];
        bz1[r] = bih1[idx] + bhh1[idx];
        bz2[r] = bih2[idx] + bhh2[idx];
    }

    short8 w2f = {};
    float b2v[4] = {0.f, 0.f, 0.f, 0.f};
    if (wv < 2) {
        int r2 = 16 * wv + b;
        int rc = r2 < OUTN ? r2 : OUTN - 1;
        w2f = load_frag_plain(W2, rc, k0);
#pragma unroll
        for (int r = 0; r < 4; ++r) {
            int rr = 16 * wv + 4 * q + r;
            b2v[r] = (rr < OUTN) ? b2[rr] : 0.0f;
        }
    }

    float c0 = 0.f, c1 = 0.f, c2 = 0.f;
    const floatx4 zero4 = {0.f, 0.f, 0.f, 0.f};

    __syncthreads();   // x staged, h zeroed

    // ---- prologue: iter k=0 (layer0@t=0 only; h0(-1)=0 so z0 = rank1+bias) ----
    {
        float xv = xs[b][0];
        float i0 = fast_sigmoid(xv * wx0[0] + bz0[0]);
        float g0 = fast_tanh   (xv * wx0[2] + bz0[2]);
        float o0 = fast_sigmoid(xv * wx0[3] + bz0[3]);
        c0 = i0 * g0;
        h0s[0][uc][b][ue] = to_bf16(o0 * fast_tanh(c0));
        __syncthreads();
    }
    // ---- prologue: iter k=1 (layer0@t=1, layer1@t=0) ----
    {
        short8 bh0 = *(const short8*)&h0s[0][q][b][0];
        floatx4 z0 = __builtin_amdgcn_mfma_f32_16x16x32_bf16(whh0f, bh0, zero4, 0, 0, 0);
        floatx4 z1 = __builtin_amdgcn_mfma_f32_16x16x32_bf16(wih1f, bh0, zero4, 0, 0, 0);
        float xv = xs[b][1];
        float i0 = fast_sigmoid(z0[0] + xv * wx0[0] + bz0[0]);
        float f0 = fast_sigmoid(z0[1] + xv * wx0[1] + bz0[1]);
        float g0 = fast_tanh   (z0[2] + xv * wx0[2] + bz0[2]);
        float o0 = fast_sigmoid(z0[3] + xv * wx0[3] + bz0[3]);
        c0 = f0 * c0 + i0 * g0;
        unsigned short h0b = to_bf16(o0 * fast_tanh(c0));
        float i1 = fast_sigmoid(z1[0] + bz1[0]);
        float g1 = fast_tanh   (z1[2] + bz1[2]);
        float o1 = fast_sigmoid(z1[3] + bz1[3]);
        c1 = i1 * g1;
        unsigned short h1b = to_bf16(o1 * fast_tanh(c1));
        h0s[1][uc][b][ue] = h0b;
        h1s[1][uc][b][ue] = h1b;
        __syncthreads();
    }

    // ---- main loop: iters k=2..511, all three layers active ----
    auto STEP = [&](int t0, int wb) {
        const int rb = wb ^ 1;
        short8 bh0 = *(const short8*)&h0s[rb][q][b][0];   // h0(t0-1)
        short8 bh1 = *(const short8*)&h1s[rb][q][b][0];   // h1(t0-2)
        short8 bh2 = *(const short8*)&h2s[rb][q][b][0];   // h2(t0-3)
        floatx4 z0 = __builtin_amdgcn_mfma_f32_16x16x32_bf16(whh0f, bh0, zero4, 0, 0, 0);
        floatx4 z1 = __builtin_amdgcn_mfma_f32_16x16x32_bf16(whh1f, bh1, zero4, 0, 0, 0);
        floatx4 z2 = __builtin_amdgcn_mfma_f32_16x16x32_bf16(whh2f, bh2, zero4, 0, 0, 0);
        z1 = __builtin_amdgcn_mfma_f32_16x16x32_bf16(wih1f, bh0, z1, 0, 0, 0);
        z2 = __builtin_amdgcn_mfma_f32_16x16x32_bf16(wih2f, bh1, z2, 0, 0, 0);
        float xv = xs[b][t0];
        // layer 0 @ t0
        float i0 = fast_sigmoid(z0[0] + xv * wx0[0] + bz0[0]);
        float f0 = fast_sigmoid(z0[1] + xv * wx0[1] + bz0[1]);
        float g0 = fast_tanh   (z0[2] + xv * wx0[2] + bz0[2]);
        float o0 = fast_sigmoid(z0[3] + xv * wx0[3] + bz0[3]);
        c0 = f0 * c0 + i0 * g0;
        unsigned short h0b = to_bf16(o0 * fast_tanh(c0));
        // layer 1 @ t0-1
        float i1 = fast_sigmoid(z1[0] + bz1[0]);
        float f1 = fast_sigmoid(z1[1] + bz1[1]);
        float g1 = fast_tanh   (z1[2] + bz1[2]);
        float o1 = fast_sigmoid(z1[3] + bz1[3]);
        c1 = f1 * c1 + i1 * g1;
        unsigned short h1b = to_bf16(o1 * fast_tanh(c1));
        // layer 2 @ t0-2
        float i2 = fast_sigmoid(z2[0] + bz2[0]);
        float f2 = fast_sigmoid(z2[1] + bz2[1]);
        float g2 = fast_tanh   (z2[2] + bz2[2]);
        float o2 = fast_sigmoid(z2[3] + bz2[3]);
        c2 = f2 * c2 + i2 * g2;
        unsigned short h2b = to_bf16(o2 * fast_tanh(c2));
        h0s[wb][uc][b][ue] = h0b;
        h1s[wb][uc][b][ue] = h1b;
        h2s[wb][uc][b][ue] = h2b;
        __syncthreads();
    };
    for (int k = 2; k < TT; k += 2) { STEP(k, 0); STEP(k + 1, 1); }

    // ---- epilogue: iter k=512 (layer1@511, layer2@510) ----
    {
        short8 bh0 = *(const short8*)&h0s[1][q][b][0];   // h0(511)
        short8 bh1 = *(const short8*)&h1s[1][q][b][0];   // h1(510)
        short8 bh2 = *(const short8*)&h2s[1][q][b][0];   // h2(509)
        floatx4 z1 = __builtin_amdgcn_mfma_f32_16x16x32_bf16(whh1f, bh1, zero4, 0, 0, 0);
        floatx4 z2 = __builtin_amdgcn_mfma_f32_16x16x32_bf16(whh2f, bh2, zero4, 0, 0, 0);
        z1 = __builtin_amdgcn_mfma_f32_16x16x32_bf16(wih1f, bh0, z1, 0, 0, 0);
        z2 = __builtin_amdgcn_mfma_f32_16x16x32_bf16(wih2f, bh1, z2, 0, 0, 0);
        float i1 = fast_sigmoid(z1[0] + bz1[0]);
        float f1 = fast_sigmoid(z1[1] + bz1[1]);
        float g1 = fast_tanh   (z1[2] + bz1[2]);
        float o1 = fast_sigmoid(z1[3] + bz1[3]);
        c1 = f1 * c1 + i1 * g1;
        unsigned short h1b = to_bf16(o1 * fast_tanh(c1));
        float i2 = fast_sigmoid(z2[0] + bz2[0]);
        float f2 = fast_sigmoid(z2[1] + bz2[1]);
        float g2 = fast_tanh   (z2[2] + bz2[2]);
        float o2 = fast_sigmoid(z2[3] + bz2[3]);
        c2 = f2 * c2 + i2 * g2;
        unsigned short h2b = to_bf16(o2 * fast_tanh(c2));
        h1s[0][uc][b][ue] = h1b;
        h2s[0][uc][b][ue] = h2b;
        __syncthreads();
    }
    // ---- epilogue: iter k=513 (layer2@511) ----
    {
        short8 bh1 = *(const short8*)&h1s[0][q][b][0];   // h1(511)
        short8 bh2 = *(const short8*)&h2s[0][q][b][0];   // h2(510)
        floatx4 z2 = __builtin_amdgcn_mfma_f32_16x16x32_bf16(whh2f, bh2, zero4, 0, 0, 0);
        z2 = __builtin_amdgcn_mfma_f32_16x16x32_bf16(wih2f, bh1, z2, 0, 0, 0);
        float i2 = fast_sigmoid(z2[0] + bz2[0]);
        float f2 = fast_sigmoid(z2[1] + bz2[1]);
        float g2 = fast_tanh   (z2[2] + bz2[2]);
        float o2 = fast_sigmoid(z2[3] + bz2[3]);
        c2 = f2 * c2 + i2 * g2;
        h2s[1][uc][b][ue] = to_bf16(o2 * fast_tanh(c2));
        __syncthreads();
    }

    // ---- out = h2(511) @ W2^T + b2 (waves 0,1) ----
    if (wv < 2) {
        short8 bh2 = *(const short8*)&h2s[1][q][b][0];
        floatx4 zo = __builtin_amdgcn_mfma_f32_16x16x32_bf16(w2f, bh2, zero4, 0, 0, 0);
#pragma unroll
        for (int r = 0; r < 4; ++r) {
            int rr = 16 * wv + 4 * q + r;
            if (rr < OUTN)
                out[(size_t)(bt * MT + b) * OUTN + rr] = zo[r] + b2v[r];
        }
    }
}

extern "C" void kernel_launch(void* const* d_in, const int* in_sizes, int n_in,
                              void* d_out, int out_size, void* d_ws, size_t ws_size,
                              hipStream_t stream) {
    const float* x    = (const float*)d_in[0];
    const float* Wih0 = (const float*)d_in[1];
    const float* Whh0 = (const float*)d_in[2];
    const float* bih0 = (const float*)d_in[3];
    const float* bhh0 = (const float*)d_in[4];
    const float* Wih1 = (const float*)d_in[5];
    const float* Whh1 = (const float*)d_in[6];
    const float* bih1 = (const float*)d_in[7];
    const float* bhh1 = (const float*)d_in[8];
    const float* Wih2 = (const float*)d_in[9];
    const float* Whh2 = (const float*)d_in[10];
    const float* bih2 = (const float*)d_in[11];
    const float* bhh2 = (const float*)d_in[12];
    const float* W2   = (const float*)d_in[13];
    const float* b2   = (const float*)d_in[14];
    float* out = (float*)d_out;

    dim3 grid(4096 / MT);   // 256 blocks, 1/CU
    dim3 block(512);        // 8 waves
    hipLaunchKernelGGL(lstm_fused, grid, block, 0, stream,
                       x, Wih0, Whh0, bih0, bhh0,
                       Wih1, Whh1, bih1, bhh1,
                       Wih2, Whh2, bih2, bhh2, W2, b2, out);
}

// Round 3
// 255.697 us; speedup vs baseline: 1.5634x; 1.1103x over previous
//
#include <hip/hip_runtime.h>
#include <cstdint>
#include <cstddef>

#define TT   512   // sequence length
#define MT   16    // batch per block (one MFMA N-tile)
#define OUTN 30    // output features

typedef __attribute__((ext_vector_type(8))) short short8;
typedef __attribute__((ext_vector_type(4))) float floatx4;

#define NLOG2E  (-1.4426950408889634f)   // sigmoid rows: z' = -log2e * z
#define N2LOG2E (-2.8853900817779268f)   // tanh rows:    z' = -2log2e * z

static __device__ __forceinline__ float rcpf(float x) { return __builtin_amdgcn_rcpf(x); }
static __device__ __forceinline__ float ex2(float x)  { return __builtin_amdgcn_exp2f(x); }

// single-instruction RNE f32->bf16
static __device__ __forceinline__ unsigned short cvt_bf16(float f) {
    unsigned int r;
    asm("v_cvt_pk_bf16_f32 %0, %1, %2" : "=v"(r) : "v"(f), "v"(f));
    return (unsigned short)r;
}
static __device__ __forceinline__ unsigned short to_bf16(float f) {  // host-side-ish exact RNE (weights)
    union { float f; unsigned int u; } v; v.f = f;
    return (unsigned short)((v.u + 0x7FFFu + ((v.u >> 16) & 1u)) >> 16);
}

// gate scale by PERMUTED row's gate index: rows [i,f,g,o] -> i,f,o: -log2e ; g: -2log2e
static __device__ __forceinline__ float gate_scale(int gate) {
    return (gate == 2) ? N2LOG2E : NLOG2E;
}

// Load 8 consecutive bf16 weights from row-major [128][32], row-permuted and pre-scaled.
// perm row R holds original row (R&3)*32 + (R>>2): order [i0,f0,g0,o0, i1,...]
static __device__ __forceinline__ short8 load_frag_perm(const float* __restrict__ W, int arow, int k0) {
    int gate = arow & 3;
    int orig = gate * 32 + (arow >> 2);
    float s = gate_scale(gate);
    const float* p = W + orig * 32 + k0;
    short8 v;
#pragma unroll
    for (int e = 0; e < 8; ++e) v[e] = (short)to_bf16(s * p[e]);
    return v;
}
static __device__ __forceinline__ short8 load_frag_plain(const float* __restrict__ W, int row, int k0) {
    const float* p = W + row * 32 + k0;
    short8 v;
#pragma unroll
    for (int e = 0; e < 8; ++e) v[e] = (short)to_bf16(p[e]);
    return v;
}

// Per-element LSTM cell math on pre-scaled z' (i,f,o: -log2e*z ; g: -2log2e*z).
// 4 exp2 + 3 rcp (paired) + ~15 VALU. Returns bf16(h), updates c in-place.
static __device__ __forceinline__ unsigned short lstm_gates(floatx4 z, float& c) {
    float Di = 1.0f + ex2(z[0]);
    float Df = 1.0f + ex2(z[1]);
    float Dg = 1.0f + ex2(z[2]);
    float Do = 1.0f + ex2(z[3]);
    float rif = rcpf(Di * Df);
    float i = Df * rif;
    float f = Di * rif;
    float rgo = rcpf(Dg * Do);
    float g = __builtin_fmaf(2.0f, Do * rgo, -1.0f);   // tanh(zg)
    float o = Dg * rgo;
    c = __builtin_fmaf(f, c, i * g);
    float tc = rcpf(1.0f + ex2(N2LOG2E * c));          // tanh(c) = 2tc-1
    float h = __builtin_fmaf(o + o, tc, -o);           // o*(2tc-1)
    return cvt_bf16(h);
}

// Grid: 256 blocks (16-batch tiles). Block: 512 threads = 8 waves.
// Wave wv owns permuted gate-rows [16wv,16wv+16) = units 4wv..4wv+3.
// Lane l: b=l&15 (batch/MFMA col), q=l>>4, unit u=4wv+q, k-chunk k0=8q.
// Software pipeline: iter k computes layer0@t=k, layer1@t=k-1, layer2@t=k-2.
// All 5 MFMAs read only last-iteration h -> ONE barrier per iteration.
// h layout [buf][q-chunk][b][8 u16]: ds_read_b128 addr16 == laneid (conflict-free).
__global__ __launch_bounds__(512, 2) void lstm_fused(
    const float* __restrict__ x,
    const float* __restrict__ Wih0, const float* __restrict__ Whh0,
    const float* __restrict__ bih0, const float* __restrict__ bhh0,
    const float* __restrict__ Wih1, const float* __restrict__ Whh1,
    const float* __restrict__ bih1, const float* __restrict__ bhh1,
    const float* __restrict__ Wih2, const float* __restrict__ Whh2,
    const float* __restrict__ bih2, const float* __restrict__ bhh2,
    const float* __restrict__ W2,   const float* __restrict__ b2,
    float* __restrict__ out)
{
    __shared__ float xs[MT][TT + 4];                // stride 516 floats (16B-aligned rows)
    __shared__ unsigned short h0s[2][4][MT][8];     // linear-in-lane b128 reads
    __shared__ unsigned short h1s[2][4][MT][8];
    __shared__ unsigned short h2s[2][4][MT][8];

    const int tid  = (int)threadIdx.x;
    const int wv   = tid >> 6;
    const int l    = tid & 63;
    const int b    = l & 15;
    const int q    = l >> 4;
    const int u    = 4 * wv + q;
    const int uc   = u >> 3, ue = u & 7;
    const int bt   = (int)blockIdx.x;
    const int arow = 16 * wv + b;
    const int k0   = q * 8;

    // ---- stage x tile [16][512] ----
    {
        const floatx4* xg = (const floatx4*)(x + (size_t)bt * MT * TT);
#pragma unroll
        for (int j = 0; j < 4; ++j) {
            int idx = tid + j * 512;
            int row = idx >> 7;
            int c4  = idx & 127;
            *(floatx4*)&xs[row][c4 * 4] = xg[idx];
        }
    }

    // ---- VGPR-resident pre-scaled weight fragments ----
    short8 whh0f = load_frag_perm(Whh0, arow, k0);
    short8 wih1f = load_frag_perm(Wih1, arow, k0);
    short8 whh1f = load_frag_perm(Whh1, arow, k0);
    short8 wih2f = load_frag_perm(Wih2, arow, k0);
    short8 whh2f = load_frag_perm(Whh2, arow, k0);

    // pre-scaled rank-1 x weights + fused biases (per lane: gates r of unit u)
    float wx0[4];
    floatx4 bc0, bc1, bc2;
#pragma unroll
    for (int r = 0; r < 4; ++r) {
        int idx = r * 32 + u;
        float s = gate_scale(r);
        wx0[r] = s * Wih0[idx];
        bc0[r] = s * (bih0[idx] + bhh0[idx]);
        bc1[r] = s * (bih1[idx] + bhh1[idx]);
        bc2[r] = s * (bih2[idx] + bhh2[idx]);
    }

    short8 w2f = {};
    floatx4 b2c = {0.f, 0.f, 0.f, 0.f};
    if (wv < 2) {
        int r2 = 16 * wv + b;
        int rc = r2 < OUTN ? r2 : OUTN - 1;
        w2f = load_frag_plain(W2, rc, k0);
#pragma unroll
        for (int r = 0; r < 4; ++r) {
            int rr = 16 * wv + 4 * q + r;
            b2c[r] = (rr < OUTN) ? b2[rr] : 0.0f;
        }
    }

    float c0 = 0.f, c1 = 0.f, c2 = 0.f;

    __syncthreads();   // x staged

    // x-term folded into the MFMA C operand (off the post-MFMA critical path)
    auto bc0x = [&](float xv) {
        floatx4 c4v;
#pragma unroll
        for (int r = 0; r < 4; ++r) c4v[r] = __builtin_fmaf(xv, wx0[r], bc0[r]);
        return c4v;
    };

    // ---- prologue k=0: layer0@0 (no MFMA, h0(-1)=0) ----
    {
        floatx4 z0 = bc0x(xs[b][0]);
        h0s[0][uc][b][ue] = lstm_gates(z0, c0);
        __syncthreads();
    }
    // ---- prologue k=1: layer0@1, layer1@0 (no whh1 term) ----
    {
        short8 bh0 = *(const short8*)&h0s[0][q][b][0];
        floatx4 z0 = __builtin_amdgcn_mfma_f32_16x16x32_bf16(whh0f, bh0, bc0x(xs[b][1]), 0, 0, 0);
        floatx4 z1 = __builtin_amdgcn_mfma_f32_16x16x32_bf16(wih1f, bh0, bc1, 0, 0, 0);
        unsigned short h0b = lstm_gates(z0, c0);
        unsigned short h1b = lstm_gates(z1, c1);
        h0s[1][uc][b][ue] = h0b;
        h1s[1][uc][b][ue] = h1b;
        __syncthreads();
    }
    // ---- prologue k=2: layer0@2, layer1@1, layer2@0 (no whh2 term) ----
    {
        short8 bh0 = *(const short8*)&h0s[1][q][b][0];
        short8 bh1 = *(const short8*)&h1s[1][q][b][0];
        floatx4 z0 = __builtin_amdgcn_mfma_f32_16x16x32_bf16(whh0f, bh0, bc0x(xs[b][2]), 0, 0, 0);
        floatx4 z1 = __builtin_amdgcn_mfma_f32_16x16x32_bf16(whh1f, bh1, bc1, 0, 0, 0);
        z1 = __builtin_amdgcn_mfma_f32_16x16x32_bf16(wih1f, bh0, z1, 0, 0, 0);
        floatx4 z2 = __builtin_amdgcn_mfma_f32_16x16x32_bf16(wih2f, bh1, bc2, 0, 0, 0);
        unsigned short h0b = lstm_gates(z0, c0);
        unsigned short h1b = lstm_gates(z1, c1);
        unsigned short h2b = lstm_gates(z2, c2);
        h0s[0][uc][b][ue] = h0b;
        h1s[0][uc][b][ue] = h1b;
        h2s[0][uc][b][ue] = h2b;
        __syncthreads();
    }

    // ---- generic full step ----
    auto STEP = [&](float xv, int wb) {
        const int rb = wb ^ 1;
        short8 bh0 = *(const short8*)&h0s[rb][q][b][0];   // h0(t-1)
        short8 bh1 = *(const short8*)&h1s[rb][q][b][0];   // h1(t-2)
        short8 bh2 = *(const short8*)&h2s[rb][q][b][0];   // h2(t-3)
        floatx4 z0 = __builtin_amdgcn_mfma_f32_16x16x32_bf16(whh0f, bh0, bc0x(xv), 0, 0, 0);
        floatx4 z1 = __builtin_amdgcn_mfma_f32_16x16x32_bf16(whh1f, bh1, bc1, 0, 0, 0);
        floatx4 z2 = __builtin_amdgcn_mfma_f32_16x16x32_bf16(whh2f, bh2, bc2, 0, 0, 0);
        z1 = __builtin_amdgcn_mfma_f32_16x16x32_bf16(wih1f, bh0, z1, 0, 0, 0);
        z2 = __builtin_amdgcn_mfma_f32_16x16x32_bf16(wih2f, bh1, z2, 0, 0, 0);
        unsigned short h0b = lstm_gates(z0, c0);
        unsigned short h1b = lstm_gates(z1, c1);
        unsigned short h2b = lstm_gates(z2, c2);
        h0s[wb][uc][b][ue] = h0b;
        h1s[wb][uc][b][ue] = h1b;
        h2s[wb][uc][b][ue] = h2b;
        __syncthreads();
    };

    // ---- k=3: single full step (scalar x read); after: writes in buf 1 ----
    STEP(xs[b][3], 1);

    // ---- main loop k=4..511: 127 x 4-step chunks, x via one b128 read ----
    for (int k = 4; k < TT; k += 4) {
        floatx4 xq = *(const floatx4*)&xs[b][k];
        STEP(xq[0], 0);
        STEP(xq[1], 1);
        STEP(xq[2], 0);
        STEP(xq[3], 1);
    }
    // state now: h0(511),h1(510),h2(509) in buf 1

    // ---- epilogue k=512: layer1@511, layer2@510 ----
    {
        short8 bh0 = *(const short8*)&h0s[1][q][b][0];
        short8 bh1 = *(const short8*)&h1s[1][q][b][0];
        short8 bh2 = *(const short8*)&h2s[1][q][b][0];
        floatx4 z1 = __builtin_amdgcn_mfma_f32_16x16x32_bf16(whh1f, bh1, bc1, 0, 0, 0);
        z1 = __builtin_amdgcn_mfma_f32_16x16x32_bf16(wih1f, bh0, z1, 0, 0, 0);
        floatx4 z2 = __builtin_amdgcn_mfma_f32_16x16x32_bf16(whh2f, bh2, bc2, 0, 0, 0);
        z2 = __builtin_amdgcn_mfma_f32_16x16x32_bf16(wih2f, bh1, z2, 0, 0, 0);
        unsigned short h1b = lstm_gates(z1, c1);
        unsigned short h2b = lstm_gates(z2, c2);
        h1s[0][uc][b][ue] = h1b;
        h2s[0][uc][b][ue] = h2b;
        __syncthreads();
    }
    // ---- epilogue k=513: layer2@511 ----
    {
        short8 bh1 = *(const short8*)&h1s[0][q][b][0];
        short8 bh2 = *(const short8*)&h2s[0][q][b][0];
        floatx4 z2 = __builtin_amdgcn_mfma_f32_16x16x32_bf16(whh2f, bh2, bc2, 0, 0, 0);
        z2 = __builtin_amdgcn_mfma_f32_16x16x32_bf16(wih2f, bh1, z2, 0, 0, 0);
        h2s[1][uc][b][ue] = lstm_gates(z2, c2);
        __syncthreads();
    }

    // ---- out = h2(511) @ W2^T + b2 (waves 0,1), bias in C ----
    if (wv < 2) {
        short8 bh2 = *(const short8*)&h2s[1][q][b][0];
        floatx4 zo = __builtin_amdgcn_mfma_f32_16x16x32_bf16(w2f, bh2, b2c, 0, 0, 0);
#pragma unroll
        for (int r = 0; r < 4; ++r) {
            int rr = 16 * wv + 4 * q + r;
            if (rr < OUTN)
                out[(size_t)(bt * MT + b) * OUTN + rr] = zo[r];
        }
    }
}

extern "C" void kernel_launch(void* const* d_in, const int* in_sizes, int n_in,
                              void* d_out, int out_size, void* d_ws, size_t ws_size,
                              hipStream_t stream) {
    const float* x    = (const float*)d_in[0];
    const float* Wih0 = (const float*)d_in[1];
    const float* Whh0 = (const float*)d_in[2];
    const float* bih0 = (const float*)d_in[3];
    const float* bhh0 = (const float*)d_in[4];
    const float* Wih1 = (const float*)d_in[5];
    const float* Whh1 = (const float*)d_in[6];
    const float* bih1 = (const float*)d_in[7];
    const float* bhh1 = (const float*)d_in[8];
    const float* Wih2 = (const float*)d_in[9];
    const float* Whh2 = (const float*)d_in[10];
    const float* bih2 = (const float*)d_in[11];
    const float* bhh2 = (const float*)d_in[12];
    const float* W2   = (const float*)d_in[13];
    const float* b2   = (const float*)d_in[14];
    float* out = (float*)d_out;

    dim3 grid(4096 / MT);   // 256 blocks, 1/CU
    dim3 block(512);        // 8 waves
    hipLaunchKernelGGL(lstm_fused, grid, block, 0, stream,
                       x, Wih0, Whh0, bih0, bhh0,
                       Wih1, Whh1, bih1, bhh1,
                       Wih2, Whh2, bih2, bhh2, W2, b2, out);
}

// Round 4
// 251.513 us; speedup vs baseline: 1.5894x; 1.0166x over previous
//
#include <hip/hip_runtime.h>
#include <cstdint>
#include <cstddef>

#define TT   512   // sequence length
#define MT   16    // batch per block (one MFMA N-tile)
#define OUTN 30    // output features

typedef __attribute__((ext_vector_type(8))) short short8;
typedef __attribute__((ext_vector_type(4))) float floatx4;

#define NLOG2E  (-1.4426950408889634f)   // sigmoid rows: z' = -log2e * z
#define N2LOG2E (-2.8853900817779268f)   // tanh rows:    z' = -2log2e * z

static __device__ __forceinline__ float rcpf(float x) { return __builtin_amdgcn_rcpf(x); }
static __device__ __forceinline__ float ex2(float x)  { return __builtin_amdgcn_exp2f(x); }

// single-instruction RNE f32->bf16
static __device__ __forceinline__ unsigned short cvt_bf16(float f) {
    unsigned int r;
    asm("v_cvt_pk_bf16_f32 %0, %1, %2" : "=v"(r) : "v"(f), "v"(f));
    return (unsigned short)r;
}
static __device__ __forceinline__ unsigned short to_bf16(float f) {  // exact RNE (weight preload)
    union { float f; unsigned int u; } v; v.f = f;
    return (unsigned short)((v.u + 0x7FFFu + ((v.u >> 16) & 1u)) >> 16);
}

// gate scale by PERMUTED row's gate index: rows [i,f,g,o] -> i,f,o: -log2e ; g: -2log2e
static __device__ __forceinline__ float gate_scale(int gate) {
    return (gate == 2) ? N2LOG2E : NLOG2E;
}

// Load 8 consecutive bf16 weights from row-major [128][32], row-permuted and pre-scaled.
// perm row R holds original row (R&3)*32 + (R>>2): order [i0,f0,g0,o0, i1,...]
static __device__ __forceinline__ short8 load_frag_perm(const float* __restrict__ W, int arow, int k0) {
    int gate = arow & 3;
    int orig = gate * 32 + (arow >> 2);
    float s = gate_scale(gate);
    const float* p = W + orig * 32 + k0;
    short8 v;
#pragma unroll
    for (int e = 0; e < 8; ++e) v[e] = (short)to_bf16(s * p[e]);
    return v;
}
static __device__ __forceinline__ short8 load_frag_plain(const float* __restrict__ W, int row, int k0) {
    const float* p = W + row * 32 + k0;
    short8 v;
#pragma unroll
    for (int e = 0; e < 8; ++e) v[e] = (short)to_bf16(p[e]);
    return v;
}

// Single-layer cell math (prologue/epilogue partial steps only).
static __device__ __forceinline__ unsigned short lstm_gates(floatx4 z, float& c) {
    float Di = 1.0f + ex2(z[0]);
    float Df = 1.0f + ex2(z[1]);
    float Dg = 1.0f + ex2(z[2]);
    float Do = 1.0f + ex2(z[3]);
    float rif = rcpf(Di * Df);
    float i = Df * rif;
    float f = Di * rif;
    float rgo = rcpf(Dg * Do);
    float g = __builtin_fmaf(2.0f, Do * rgo, -1.0f);
    float o = Dg * rgo;
    c = __builtin_fmaf(f, c, i * g);
    float tc = rcpf(1.0f + ex2(N2LOG2E * c));
    float h = __builtin_fmaf(o + o, tc, -o);
    return cvt_bf16(h);
}

// Stage-parallel 3-layer cell math: identical arithmetic to 3x lstm_gates,
// but interleaved stage-by-stage so the quarter-rate trans pipe sees dense
// independent bursts (12 ex2 / 6 rcp / 3 ex2 / 3 rcp) instead of three
// serial 8-deep chains.
static __device__ __forceinline__ void gates3(floatx4 z0, floatx4 z1, floatx4 z2,
                                              float& c0, float& c1, float& c2,
                                              unsigned short& h0b, unsigned short& h1b,
                                              unsigned short& h2b) {
    // stage 1: all exponentials
    float e00 = ex2(z0[0]), e01 = ex2(z0[1]), e02 = ex2(z0[2]), e03 = ex2(z0[3]);
    float e10 = ex2(z1[0]), e11 = ex2(z1[1]), e12 = ex2(z1[2]), e13 = ex2(z1[3]);
    float e20 = ex2(z2[0]), e21 = ex2(z2[1]), e22 = ex2(z2[2]), e23 = ex2(z2[3]);
    // stage 2: denominators
    float Di0 = 1.0f + e00, Df0 = 1.0f + e01, Dg0 = 1.0f + e02, Do0 = 1.0f + e03;
    float Di1 = 1.0f + e10, Df1 = 1.0f + e11, Dg1 = 1.0f + e12, Do1 = 1.0f + e13;
    float Di2 = 1.0f + e20, Df2 = 1.0f + e21, Dg2 = 1.0f + e22, Do2 = 1.0f + e23;
    // stage 3: paired products then all reciprocals
    float p0 = Di0 * Df0, q0 = Dg0 * Do0;
    float p1 = Di1 * Df1, q1 = Dg1 * Do1;
    float p2 = Di2 * Df2, q2 = Dg2 * Do2;
    float rif0 = rcpf(p0), rgo0 = rcpf(q0);
    float rif1 = rcpf(p1), rgo1 = rcpf(q1);
    float rif2 = rcpf(p2), rgo2 = rcpf(q2);
    // stage 4: gate recovery + c update
    float i0 = Df0 * rif0, f0 = Di0 * rif0, o0 = Dg0 * rgo0;
    float i1 = Df1 * rif1, f1 = Di1 * rif1, o1 = Dg1 * rgo1;
    float i2 = Df2 * rif2, f2 = Di2 * rif2, o2 = Dg2 * rgo2;
    float g0 = __builtin_fmaf(2.0f, Do0 * rgo0, -1.0f);
    float g1 = __builtin_fmaf(2.0f, Do1 * rgo1, -1.0f);
    float g2 = __builtin_fmaf(2.0f, Do2 * rgo2, -1.0f);
    c0 = __builtin_fmaf(f0, c0, i0 * g0);
    c1 = __builtin_fmaf(f1, c1, i1 * g1);
    c2 = __builtin_fmaf(f2, c2, i2 * g2);
    // stage 5: tanh(c) chains, 3-way parallel
    float a0 = ex2(N2LOG2E * c0), a1 = ex2(N2LOG2E * c1), a2 = ex2(N2LOG2E * c2);
    float t0 = rcpf(1.0f + a0), t1 = rcpf(1.0f + a1), t2 = rcpf(1.0f + a2);
    float h0 = __builtin_fmaf(o0 + o0, t0, -o0);
    float h1 = __builtin_fmaf(o1 + o1, t1, -o1);
    float h2 = __builtin_fmaf(o2 + o2, t2, -o2);
    h0b = cvt_bf16(h0);
    h1b = cvt_bf16(h1);
    h2b = cvt_bf16(h2);
}

// Grid: 256 blocks (16-batch tiles). Block: 512 threads = 8 waves.
// Wave wv owns permuted gate-rows [16wv,16wv+16) = units 4wv..4wv+3.
// Lane l: b=l&15 (batch/MFMA col), q=l>>4, unit u=4wv+q, k-chunk k0=8q.
// Software pipeline: iter k computes layer0@t=k, layer1@t=k-1, layer2@t=k-2.
// All 5 MFMAs read only last-iteration h -> ONE barrier per iteration.
// h layout [buf][q-chunk][b][8 u16]: ds_read_b128 addr16 == laneid (conflict-free).
__global__ __launch_bounds__(512, 2) void lstm_fused(
    const float* __restrict__ x,
    const float* __restrict__ Wih0, const float* __restrict__ Whh0,
    const float* __restrict__ bih0, const float* __restrict__ bhh0,
    const float* __restrict__ Wih1, const float* __restrict__ Whh1,
    const float* __restrict__ bih1, const float* __restrict__ bhh1,
    const float* __restrict__ Wih2, const float* __restrict__ Whh2,
    const float* __restrict__ bih2, const float* __restrict__ bhh2,
    const float* __restrict__ W2,   const float* __restrict__ b2,
    float* __restrict__ out)
{
    __shared__ float xs[MT][TT + 4];                // stride 516 floats (16B-aligned rows)
    __shared__ unsigned short h0s[2][4][MT][8];     // linear-in-lane b128 reads
    __shared__ unsigned short h1s[2][4][MT][8];
    __shared__ unsigned short h2s[2][4][MT][8];

    const int tid  = (int)threadIdx.x;
    const int wv   = tid >> 6;
    const int l    = tid & 63;
    const int b    = l & 15;
    const int q    = l >> 4;
    const int u    = 4 * wv + q;
    const int uc   = u >> 3, ue = u & 7;
    const int bt   = (int)blockIdx.x;
    const int arow = 16 * wv + b;
    const int k0   = q * 8;

    // ---- stage x tile [16][512] ----
    {
        const floatx4* xg = (const floatx4*)(x + (size_t)bt * MT * TT);
#pragma unroll
        for (int j = 0; j < 4; ++j) {
            int idx = tid + j * 512;
            int row = idx >> 7;
            int c4  = idx & 127;
            *(floatx4*)&xs[row][c4 * 4] = xg[idx];
        }
    }

    // ---- VGPR-resident pre-scaled weight fragments ----
    short8 whh0f = load_frag_perm(Whh0, arow, k0);
    short8 wih1f = load_frag_perm(Wih1, arow, k0);
    short8 whh1f = load_frag_perm(Whh1, arow, k0);
    short8 wih2f = load_frag_perm(Wih2, arow, k0);
    short8 whh2f = load_frag_perm(Whh2, arow, k0);

    // pre-scaled rank-1 x weights + fused biases (per lane: gates r of unit u)
    float wx0[4];
    floatx4 bc0, bc1, bc2;
#pragma unroll
    for (int r = 0; r < 4; ++r) {
        int idx = r * 32 + u;
        float s = gate_scale(r);
        wx0[r] = s * Wih0[idx];
        bc0[r] = s * (bih0[idx] + bhh0[idx]);
        bc1[r] = s * (bih1[idx] + bhh1[idx]);
        bc2[r] = s * (bih2[idx] + bhh2[idx]);
    }

    short8 w2f = {};
    floatx4 b2c = {0.f, 0.f, 0.f, 0.f};
    if (wv < 2) {
        int r2 = 16 * wv + b;
        int rc = r2 < OUTN ? r2 : OUTN - 1;
        w2f = load_frag_plain(W2, rc, k0);
#pragma unroll
        for (int r = 0; r < 4; ++r) {
            int rr = 16 * wv + 4 * q + r;
            b2c[r] = (rr < OUTN) ? b2[rr] : 0.0f;
        }
    }

    float c0 = 0.f, c1 = 0.f, c2 = 0.f;

    __syncthreads();   // x staged

    // x-term folded into the MFMA C operand (off the post-MFMA critical path)
    auto bc0x = [&](float xv) {
        floatx4 c4v;
#pragma unroll
        for (int r = 0; r < 4; ++r) c4v[r] = __builtin_fmaf(xv, wx0[r], bc0[r]);
        return c4v;
    };

    // ---- prologue k=0: layer0@0 (no MFMA, h0(-1)=0) ----
    {
        floatx4 z0 = bc0x(xs[b][0]);
        h0s[0][uc][b][ue] = lstm_gates(z0, c0);
        __syncthreads();
    }
    // ---- prologue k=1: layer0@1, layer1@0 (no whh1 term) ----
    {
        short8 bh0 = *(const short8*)&h0s[0][q][b][0];
        floatx4 z0 = __builtin_amdgcn_mfma_f32_16x16x32_bf16(whh0f, bh0, bc0x(xs[b][1]), 0, 0, 0);
        floatx4 z1 = __builtin_amdgcn_mfma_f32_16x16x32_bf16(wih1f, bh0, bc1, 0, 0, 0);
        unsigned short h0b = lstm_gates(z0, c0);
        unsigned short h1b = lstm_gates(z1, c1);
        h0s[1][uc][b][ue] = h0b;
        h1s[1][uc][b][ue] = h1b;
        __syncthreads();
    }
    // ---- prologue k=2: layer0@2, layer1@1, layer2@0 (no whh2 term) ----
    {
        short8 bh0 = *(const short8*)&h0s[1][q][b][0];
        short8 bh1 = *(const short8*)&h1s[1][q][b][0];
        floatx4 z0 = __builtin_amdgcn_mfma_f32_16x16x32_bf16(whh0f, bh0, bc0x(xs[b][2]), 0, 0, 0);
        floatx4 z1 = __builtin_amdgcn_mfma_f32_16x16x32_bf16(whh1f, bh1, bc1, 0, 0, 0);
        z1 = __builtin_amdgcn_mfma_f32_16x16x32_bf16(wih1f, bh0, z1, 0, 0, 0);
        floatx4 z2 = __builtin_amdgcn_mfma_f32_16x16x32_bf16(wih2f, bh1, bc2, 0, 0, 0);
        unsigned short h0b, h1b, h2b;
        gates3(z0, z1, z2, c0, c1, c2, h0b, h1b, h2b);
        h0s[0][uc][b][ue] = h0b;
        h1s[0][uc][b][ue] = h1b;
        h2s[0][uc][b][ue] = h2b;
        __syncthreads();
    }

    // ---- generic full step (stage-parallel gates) ----
    auto STEP = [&](float xv, int wb) {
        const int rb = wb ^ 1;
        short8 bh0 = *(const short8*)&h0s[rb][q][b][0];   // h0(t-1)
        short8 bh1 = *(const short8*)&h1s[rb][q][b][0];   // h1(t-2)
        short8 bh2 = *(const short8*)&h2s[rb][q][b][0];   // h2(t-3)
        floatx4 z0 = __builtin_amdgcn_mfma_f32_16x16x32_bf16(whh0f, bh0, bc0x(xv), 0, 0, 0);
        floatx4 z1 = __builtin_amdgcn_mfma_f32_16x16x32_bf16(whh1f, bh1, bc1, 0, 0, 0);
        floatx4 z2 = __builtin_amdgcn_mfma_f32_16x16x32_bf16(whh2f, bh2, bc2, 0, 0, 0);
        z1 = __builtin_amdgcn_mfma_f32_16x16x32_bf16(wih1f, bh0, z1, 0, 0, 0);
        z2 = __builtin_amdgcn_mfma_f32_16x16x32_bf16(wih2f, bh1, z2, 0, 0, 0);
        unsigned short h0b, h1b, h2b;
        gates3(z0, z1, z2, c0, c1, c2, h0b, h1b, h2b);
        h0s[wb][uc][b][ue] = h0b;
        h1s[wb][uc][b][ue] = h1b;
        h2s[wb][uc][b][ue] = h2b;
        __syncthreads();
    };

    // ---- k=3: single full step (scalar x read); after: writes in buf 1 ----
    STEP(xs[b][3], 1);

    // ---- main loop k=4..511: 127 x 4-step chunks, x via one b128 read ----
    for (int k = 4; k < TT; k += 4) {
        floatx4 xq = *(const floatx4*)&xs[b][k];
        STEP(xq[0], 0);
        STEP(xq[1], 1);
        STEP(xq[2], 0);
        STEP(xq[3], 1);
    }
    // state now: h0(511),h1(510),h2(509) in buf 1

    // ---- epilogue k=512: layer1@511, layer2@510 ----
    {
        short8 bh0 = *(const short8*)&h0s[1][q][b][0];
        short8 bh1 = *(const short8*)&h1s[1][q][b][0];
        short8 bh2 = *(const short8*)&h2s[1][q][b][0];
        floatx4 z1 = __builtin_amdgcn_mfma_f32_16x16x32_bf16(whh1f, bh1, bc1, 0, 0, 0);
        z1 = __builtin_amdgcn_mfma_f32_16x16x32_bf16(wih1f, bh0, z1, 0, 0, 0);
        floatx4 z2 = __builtin_amdgcn_mfma_f32_16x16x32_bf16(whh2f, bh2, bc2, 0, 0, 0);
        z2 = __builtin_amdgcn_mfma_f32_16x16x32_bf16(wih2f, bh1, z2, 0, 0, 0);
        unsigned short h1b = lstm_gates(z1, c1);
        unsigned short h2b = lstm_gates(z2, c2);
        h1s[0][uc][b][ue] = h1b;
        h2s[0][uc][b][ue] = h2b;
        __syncthreads();
    }
    // ---- epilogue k=513: layer2@511 ----
    {
        short8 bh1 = *(const short8*)&h1s[0][q][b][0];
        short8 bh2 = *(const short8*)&h2s[0][q][b][0];
        floatx4 z2 = __builtin_amdgcn_mfma_f32_16x16x32_bf16(whh2f, bh2, bc2, 0, 0, 0);
        z2 = __builtin_amdgcn_mfma_f32_16x16x32_bf16(wih2f, bh1, z2, 0, 0, 0);
        h2s[1][uc][b][ue] = lstm_gates(z2, c2);
        __syncthreads();
    }

    // ---- out = h2(511) @ W2^T + b2 (waves 0,1), bias in C ----
    if (wv < 2) {
        short8 bh2 = *(const short8*)&h2s[1][q][b][0];
        floatx4 zo = __builtin_amdgcn_mfma_f32_16x16x32_bf16(w2f, bh2, b2c, 0, 0, 0);
#pragma unroll
        for (int r = 0; r < 4; ++r) {
            int rr = 16 * wv + 4 * q + r;
            if (rr < OUTN)
                out[(size_t)(bt * MT + b) * OUTN + rr] = zo[r];
        }
    }
}

extern "C" void kernel_launch(void* const* d_in, const int* in_sizes, int n_in,
                              void* d_out, int out_size, void* d_ws, size_t ws_size,
                              hipStream_t stream) {
    const float* x    = (const float*)d_in[0];
    const float* Wih0 = (const float*)d_in[1];
    const float* Whh0 = (const float*)d_in[2];
    const float* bih0 = (const float*)d_in[3];
    const float* bhh0 = (const float*)d_in[4];
    const float* Wih1 = (const float*)d_in[5];
    const float* Whh1 = (const float*)d_in[6];
    const float* bih1 = (const float*)d_in[7];
    const float* bhh1 = (const float*)d_in[8];
    const float* Wih2 = (const float*)d_in[9];
    const float* Whh2 = (const float*)d_in[10];
    const float* bih2 = (const float*)d_in[11];
    const float* bhh2 = (const float*)d_in[12];
    const float* W2   = (const float*)d_in[13];
    const float* b2   = (const float*)d_in[14];
    float* out = (float*)d_out;

    dim3 grid(4096 / MT);   // 256 blocks, 1/CU
    dim3 block(512);        // 8 waves
    hipLaunchKernelGGL(lstm_fused, grid, block, 0, stream,
                       x, Wih0, Whh0, bih0, bhh0,
                       Wih1, Whh1, bih1, bhh1,
                       Wih2, Whh2, bih2, bhh2, W2, b2, out);
}